// Round 6
// baseline (199.917 us; speedup 1.0000x reference)
//
#include <hip/hip_runtime.h>

typedef unsigned int u32;
typedef unsigned short u16;
typedef __attribute__((ext_vector_type(2))) float f32x2;
typedef __attribute__((ext_vector_type(4))) float f32x4;
typedef __attribute__((ext_vector_type(8))) __bf16 bf16x8;
typedef __attribute__((ext_vector_type(4))) u32 u32x4;

// fp32 -> bf16 round-to-nearest-even
__device__ __forceinline__ u32 f2bf(float f) {
    u32 u = __builtin_bit_cast(u32, f);
    return (u + 0x7fffu + ((u >> 16) & 1u)) >> 16;
}
__device__ __forceinline__ u32 pk2(float lo, float hi) {
    return f2bf(lo) | (f2bf(hi) << 16);
}
// unpack bf16 pair from u32 (do NOT use __bf16 vector arithmetic on gfx950 —
// prior session showed it miscompiles; unpack to f32 explicitly)
__device__ __forceinline__ float bflo(u32 a) { return __builtin_bit_cast(float, a << 16); }
__device__ __forceinline__ float bfhi(u32 a) { return __builtin_bit_cast(float, a & 0xffff0000u); }

union LdsTile {
    u16 h[16 * 136];
    u32x4 v[16 * 17];
};

// ---------------------------------------------------------------------------
// Precompute kernel R12: kill the scalar W1 preload + raise occupancy.
//   R5 analysis: old version built wf[8][4] (128 VGPRs) via 512 scalar
//   stride-512B loads per thread, and the 128-reg weight block forced ~220
//   VGPR -> (256,2) -> 8 waves/CU for a streaming kernel. New scheme:
//   one cooperative coalesced pass stages W1 fragments into LDS (32 KB, in
//   the exact MFMA B-fragment layout), the MFMA loop ds_read_b128's each
//   fragment on demand (8 regs live per kk instead of 128). VGPR ~110 ->
//   (256,3), 12 waves/CU; grid 768 = exactly 3 blocks/CU, 2 tiles/wave.
//   Fragment map: wf[nt][kk][jp] = pk2(W[k][col], W[k+1][col]),
//   k = kk*32+q*8+jp*2, col = nt*16+n. Fill from row-pair rp (k=2rp):
//   kk=rp>>4, q=(rp>>2)&3, jp=rp&3; nt=c>>4, n=c&15.
//   LDS read wfrag[nt][kk][q][n]: lane (n,q) -> dword (q*64+n*4), banks
//   n*4%32 -> 8 lanes/bank-quad == the wave64 b128 floor (effectively
//   conflict-free).
// ---------------------------------------------------------------------------
__global__ __launch_bounds__(256, 3)
void precompute_kernel(const float* __restrict__ x_nbr,
                       const float* __restrict__ x_agent,
                       const float* __restrict__ W1,
                       const float* __restrict__ b1,
                       const float* __restrict__ Wa,
                       const float* __restrict__ ba,
                       u16* __restrict__ np, u16* __restrict__ ap,
                       float* __restrict__ out,
                       int n_nodes, int n_agents, int nbr_blocks)
{
    __shared__ LdsTile Abuf[4];
    __shared__ u32x4 wfrag[8][4][4][16];   // 32 KB: [nt][kk][q][n]
    const int wid = threadIdx.x >> 6;
    const int l   = threadIdx.x & 63;
    const int n   = l & 15;
    const int q   = l >> 4;
    const bool is_nbr = (int)blockIdx.x < nbr_blocks;

    const float* Wb = W1 + (is_nbr ? 0 : 128 * 128);

    // ---- cooperative W1-fragment staging (fully coalesced) ----
    {
        const int tid  = threadIdx.x;
        const int c    = tid & 127;         // column
        const int half = tid >> 7;          // 0/1: which row-pair this iter
#pragma unroll 4
        for (int it = 0; it < 32; ++it) {
            const int rp = it * 2 + half;   // row pair 0..63, k = 2*rp
            const int k  = rp * 2;
            const float f0 = Wb[(size_t)k * 128 + c];
            const float f1 = Wb[(size_t)(k + 1) * 128 + c];
            wfrag[c >> 4][rp >> 4][(rp >> 2) & 3][c & 15][rp & 3] = pk2(f0, f1);
        }
    }
    __syncthreads();

    const f32x4 zero = {0.f, 0.f, 0.f, 0.f};

    if (is_nbr) {
        const int n_tiles = n_nodes >> 4;
        const int gw = blockIdx.x * 4 + wid;
        const int stride = nbr_blocks * 4;
        for (int t = gw; t < n_tiles; t += stride) {
            const int a0 = t * 16;
#pragma unroll
            for (int it = 0; it < 4; ++it) {
                const int m = it * 4 + q;
                const float* bp = x_nbr + (size_t)(a0 + m) * 128 + n * 8;
                const float4 v0 = *(const float4*)bp;
                const float4 v1 = *(const float4*)(bp + 4);
                u32x4 pkv;
                pkv[0] = pk2(v0.x, v0.y); pkv[1] = pk2(v0.z, v0.w);
                pkv[2] = pk2(v1.x, v1.y); pkv[3] = pk2(v1.z, v1.w);
                Abuf[wid].v[m * 17 + n] = pkv;
            }
            f32x4 acc[8];
#pragma unroll
            for (int nt = 0; nt < 8; ++nt) acc[nt] = zero;
#pragma unroll
            for (int kk = 0; kk < 4; ++kk) {
                const u32x4 a = Abuf[wid].v[n * 17 + kk * 4 + q];
                u32x4 wv[8];
#pragma unroll
                for (int nt = 0; nt < 8; ++nt) wv[nt] = wfrag[nt][kk][q][n];
#pragma unroll
                for (int nt = 0; nt < 8; ++nt)
                    acc[nt] = __builtin_amdgcn_mfma_f32_16x16x32_bf16(
                        __builtin_bit_cast(bf16x8, a),
                        __builtin_bit_cast(bf16x8, wv[nt]), acc[nt], 0, 0, 0);
            }
#pragma unroll
            for (int nt = 0; nt < 8; ++nt)
#pragma unroll
                for (int r = 0; r < 4; ++r)
                    np[(size_t)(a0 + q * 4 + r) * 128 + nt * 16 + n] =
                        (u16)f2bf(acc[nt][r]);
        }
    } else {
        u32x4 waf[4];
#pragma unroll
        for (int kk = 0; kk < 4; ++kk) {
            u32x4 w;
#pragma unroll
            for (int jp = 0; jp < 4; ++jp) {
                const int k = kk * 32 + q * 8 + jp * 2;
                const float f0 = (n < 8) ? Wa[(size_t)k * 8 + n] : 0.f;
                const float f1 = (n < 8) ? Wa[(size_t)(k + 1) * 8 + n] : 0.f;
                w[jp] = pk2(f0, f1);
            }
            waf[kk] = w;
        }
        float b1v[8];
#pragma unroll
        for (int nt = 0; nt < 8; ++nt) b1v[nt] = b1[nt * 16 + n];
        const float bav = (n < 8) ? ba[n] : 0.f;

        const int n_tiles = n_agents >> 4;
        const int agent_blocks = gridDim.x - nbr_blocks;
        const int gw = (blockIdx.x - nbr_blocks) * 4 + wid;
        const int stride = agent_blocks * 4;
        for (int t = gw; t < n_tiles; t += stride) {
            const int a0 = t * 16;
#pragma unroll
            for (int it = 0; it < 4; ++it) {
                const int m = it * 4 + q;
                const float* bp = x_agent + (size_t)(a0 + m) * 128 + n * 8;
                const float4 v0 = *(const float4*)bp;
                const float4 v1 = *(const float4*)(bp + 4);
                u32x4 pkv;
                pkv[0] = pk2(v0.x, v0.y); pkv[1] = pk2(v0.z, v0.w);
                pkv[2] = pk2(v1.x, v1.y); pkv[3] = pk2(v1.z, v1.w);
                Abuf[wid].v[m * 17 + n] = pkv;
            }
            f32x4 acc[8];
#pragma unroll
            for (int nt = 0; nt < 8; ++nt) acc[nt] = zero;
            f32x4 acca = zero;
#pragma unroll
            for (int kk = 0; kk < 4; ++kk) {
                const u32x4 a = Abuf[wid].v[n * 17 + kk * 4 + q];
                u32x4 wv[8];
#pragma unroll
                for (int nt = 0; nt < 8; ++nt) wv[nt] = wfrag[nt][kk][q][n];
#pragma unroll
                for (int nt = 0; nt < 8; ++nt)
                    acc[nt] = __builtin_amdgcn_mfma_f32_16x16x32_bf16(
                        __builtin_bit_cast(bf16x8, a),
                        __builtin_bit_cast(bf16x8, wv[nt]), acc[nt], 0, 0, 0);
                acca = __builtin_amdgcn_mfma_f32_16x16x32_bf16(
                    __builtin_bit_cast(bf16x8, a),
                    __builtin_bit_cast(bf16x8, waf[kk]), acca, 0, 0, 0);
            }
#pragma unroll
            for (int nt = 0; nt < 8; ++nt)
#pragma unroll
                for (int r = 0; r < 4; ++r)
                    ap[(size_t)(a0 + q * 4 + r) * 128 + nt * 16 + n] =
                        (u16)f2bf(acc[nt][r] + b1v[nt]);
            const float4 z = {0.f, 0.f, 0.f, 0.f};
#pragma unroll
            for (int it = 0; it < 4; ++it) {
                const int m = it * 4 + q;
                float4* zp = (float4*)(out + (size_t)(a0 + m) * 264 + 128 + n * 8);
                zp[0] = z; zp[1] = z;
            }
#pragma unroll
            for (int r = 0; r < 4; ++r) {
                const int m = q * 4 + r;
                if (n < 8) out[(size_t)(a0 + m) * 264 + 256 + n] = acca[r] + bav;
            }
        }
    }
}

// ---------------------------------------------------------------------------
// Edge kernel R11 (UNCHANGED from R5 — verified 42.4us, VGPR 64, no spill):
// 2-deep ISA pipeline, progressive per-pair vmcnt waits, packed relu+cvt.
//   Ledger: per-step ops A=1 idx, B=8 gathers (interleaved np/ap), D=4
//   stores = 13. W1 wait vmcnt(13); compute pair kk waits 19-2kk.
//   Prologue pair kk waits 15-2kk. dst(tile t)==t (fixture structure).
// ---------------------------------------------------------------------------
struct GSet { u32x4 np[4]; u32x4 ap[4]; };

__device__ __forceinline__ void async_idx(const int* p, int& v) {
    asm volatile("global_load_dword %0, %1, off" : "=v"(v) : "v"(p) : "memory");
}
// 8 gathers, interleaved np/ap pairs so pair kk sits at FIFO slots 2kk+1,2kk+2
__device__ __forceinline__ void issue_block(const u16* npb, const u16* apb, GSet& g) {
    asm volatile(
        "global_load_dwordx4 %0, %8, off sc0\n\t"
        "global_load_dwordx4 %1, %9, off sc0\n\t"
        "global_load_dwordx4 %2, %8, off offset:64 sc0\n\t"
        "global_load_dwordx4 %3, %9, off offset:64 sc0\n\t"
        "global_load_dwordx4 %4, %8, off offset:128 sc0\n\t"
        "global_load_dwordx4 %5, %9, off offset:128 sc0\n\t"
        "global_load_dwordx4 %6, %8, off offset:192 sc0\n\t"
        "global_load_dwordx4 %7, %9, off offset:192 sc0"
        : "=&v"(g.np[0]), "=&v"(g.ap[0]), "=&v"(g.np[1]), "=&v"(g.ap[1]),
          "=&v"(g.np[2]), "=&v"(g.ap[2]), "=&v"(g.np[3]), "=&v"(g.ap[3])
        : "v"(npb), "v"(apb) : "memory");
}
__device__ __forceinline__ void issue_gathers(const u16* __restrict__ np,
                                              const u16* __restrict__ ap,
                                              int src_self, int t, int q, GSet& g)
{
    issue_block(np + (size_t)(unsigned)src_self * 128 + q * 8,
                ap + (size_t)(unsigned)t        * 128 + q * 8, g);
}

// two-level so the count macro-expands before stringification
#define WAITP_(N, a, b) \
    asm volatile("s_waitcnt vmcnt(" #N ")" : "+v"(a), "+v"(b) :: "memory")
#define WAITP(N, a, b) WAITP_(N, a, b)

// relu(a+b) on a packed bf16 pair -> packed bf16 (v_pk_add_f32 + cvt_pk RNE)
__device__ __forceinline__ u32 relu_pk(u32 av, u32 bv) {
    f32x2 a = {bflo(av), bfhi(av)};
    f32x2 b = {bflo(bv), bfhi(bv)};
    const f32x2 s = a + b;
    const float lo = fmaxf(s[0], 0.f);
    const float hi = fmaxf(s[1], 0.f);
    u32 r;
    asm("v_cvt_pk_bf16_f32 %0, %1, %2" : "=v"(r) : "v"(lo), "v"(hi));
    return r;
}
__device__ __forceinline__ u32x4 relu_pk4(const u32x4& a, const u32x4& b) {
    u32x4 hf;
    hf[0] = relu_pk(a[0], b[0]); hf[1] = relu_pk(a[1], b[1]);
    hf[2] = relu_pk(a[2], b[2]); hf[3] = relu_pk(a[3], b[3]);
    return hf;
}

#define MFMA_BF16(A, B, C) __builtin_amdgcn_mfma_f32_16x16x32_bf16( \
    __builtin_bit_cast(bf16x8, A), __builtin_bit_cast(bf16x8, B), (C), 0, 0, 0)

// compute one tile from G with progressive per-pair waits W0..W3, then store
#define COMPUTE_TILE(G, DST, W0, W1N, W2N, W3N) do {                          \
    f32x4 acc2 = {0.f, 0.f, 0.f, 0.f};                                        \
    WAITP(W0,  (G).np[0], (G).ap[0]);                                         \
    acc2 = MFMA_BF16(relu_pk4((G).np[0], (G).ap[0]), w2f[0], acc2);           \
    WAITP(W1N, (G).np[1], (G).ap[1]);                                         \
    acc2 = MFMA_BF16(relu_pk4((G).np[1], (G).ap[1]), w2f[1], acc2);           \
    WAITP(W2N, (G).np[2], (G).ap[2]);                                         \
    acc2 = MFMA_BF16(relu_pk4((G).np[2], (G).ap[2]), w2f[2], acc2);           \
    WAITP(W3N, (G).np[3], (G).ap[3]);                                         \
    acc2 = MFMA_BF16(relu_pk4((G).np[3], (G).ap[3]), w2f[3], acc2);           \
    float* orow = out + (size_t)(DST) * 264;                                  \
    _Pragma("unroll")                                                         \
    for (int r = 0; r < 4; ++r)                                               \
        if (n < 8) orow[(q * 4 + r) * 8 + n] = acc2[r] + b2v;                 \
} while (0)

// PC = parity of the tile being computed; PF = 1-PC (tile being fetched)
template<int PC>
__device__ __forceinline__ void pipe_step(const u16* __restrict__ np,
                                          const u16* __restrict__ ap,
                                          const int* __restrict__ edge_src,
                                          float* __restrict__ out,
                                          int t_c, int t_f, int t_a,
                                          int q, int n,
                                          int (&sreg)[2], GSet (&g)[2],
                                          const u32x4 (&w2f)[4], float b2v)
{
    constexpr int PF = 1 - PC;
    // A: src idx for tile t_a (overwrites sreg[PC]: its gathers issued last step)
    async_idx(edge_src + (size_t)t_a * 16 + n, sreg[PC]);
    // W1: src idx of tile t_f resident (13 newer: B(prev)8 + D(prev)4 + A 1)
    asm volatile("s_waitcnt vmcnt(13)" : "+v"(sreg[PF]) :: "memory");
    // B: gathers for tile t_f (dst == t_f, no load needed)
    issue_gathers(np, ap, sreg[PF], t_f, q, g[PF]);
    // compute tile t_c from g[PC] with progressive waits 19/17/15/13
    COMPUTE_TILE(g[PC], t_c, 19, 17, 15, 13);
}

__global__ __launch_bounds__(256, 3)
void edge_kernel(const u16* __restrict__ np, const u16* __restrict__ ap,
                 const float* __restrict__ W2, const float* __restrict__ b2,
                 const int* __restrict__ edge_src,
                 float* __restrict__ out, int n_tiles)
{
    const int wid = threadIdx.x >> 6;
    const int l   = threadIdx.x & 63;
    const int n   = l & 15;
    const int q   = l >> 4;

    u32x4 w2f[4];
#pragma unroll
    for (int kk = 0; kk < 4; ++kk) {
        u32x4 w;
#pragma unroll
        for (int jp = 0; jp < 4; ++jp) {
            const int k = kk * 32 + q * 8 + jp * 2;
            const float f0 = (n < 8) ? W2[(size_t)k * 8 + n] : 0.f;
            const float f1 = (n < 8) ? W2[(size_t)(k + 1) * 8 + n] : 0.f;
            w[jp] = pk2(f0, f1);
        }
        w2f[kk] = w;
    }
    const float b2v = (n < 8) ? b2[n] : 0.f;

    const int stride = gridDim.x * 4;
    const int gw = blockIdx.x * 4 + wid;
    if (gw >= n_tiles) return;
    const int nt_w = (n_tiles - gw + stride - 1) / stride;

    int t_c = gw;
    int t_f = (t_c + stride < n_tiles) ? t_c + stride : t_c;
    int t_a = (t_f + stride < n_tiles) ? t_f + stride : t_f;

    int sreg[2];
    GSet g[2];

    // ---- prologue: A0, A1, wait(0), B0, A2, B1, compute0(prog waits) ----
    async_idx(edge_src + (size_t)t_c * 16 + n, sreg[0]);
    async_idx(edge_src + (size_t)t_f * 16 + n, sreg[1]);
    asm volatile("s_waitcnt vmcnt(0)" : "+v"(sreg[0]), "+v"(sreg[1]) :: "memory");
    issue_gathers(np, ap, sreg[0], t_c, q, g[0]);           // B0 (8)
    async_idx(edge_src + (size_t)t_a * 16 + n, sreg[0]);    // A2 (1) — sreg[0] free
    issue_gathers(np, ap, sreg[1], t_f, q, g[1]);           // B1 (8)
    // pair kk of B0: newer = rest-of-B0 (6-2kk) + A2 1 + B1 8 = 15-2kk
    COMPUTE_TILE(g[0], t_c, 15, 13, 11, 9);                 // D0 (4)

    // ---- steady loop: tile i uses g[i&1]; src regs by same parity ----
    int i = 1;
    while (true) {
        if (i >= nt_w) break;
        t_c = t_f; t_f = t_a;
        t_a = (t_a + stride < n_tiles) ? t_a + stride : t_a;
        pipe_step<1>(np, ap, edge_src, out, t_c, t_f, t_a,
                     q, n, sreg, g, w2f, b2v);
        if (++i >= nt_w) break;
        t_c = t_f; t_f = t_a;
        t_a = (t_a + stride < n_tiles) ? t_a + stride : t_a;
        pipe_step<0>(np, ap, edge_src, out, t_c, t_f, t_a,
                     q, n, sreg, g, w2f, b2v);
        ++i;
    }
}

extern "C" void kernel_launch(void* const* d_in, const int* in_sizes, int n_in,
                              void* d_out, int out_size, void* d_ws, size_t ws_size,
                              hipStream_t stream)
{
    const float* x_nbr   = (const float*)d_in[0];
    const float* x_agent = (const float*)d_in[1];
    const float* W1      = (const float*)d_in[2];
    const float* b1      = (const float*)d_in[3];
    const float* W2      = (const float*)d_in[4];
    const float* b2      = (const float*)d_in[5];
    const float* Wa      = (const float*)d_in[6];
    const float* ba      = (const float*)d_in[7];
    const int* edge_src  = (const int*)d_in[8];

    const int E        = in_sizes[8];
    const int n_nodes  = in_sizes[0] / 128;
    const int n_agents = in_sizes[1] / 128;
    const int n_tiles  = E / 16;

    u16* np = (u16*)d_ws;
    u16* ap = (u16*)d_ws + (size_t)n_nodes * 128;

    // 768 = exactly 3 blocks/CU at (256,3); ~2 balanced tiles/wave per path
    const int nbr_blocks = 384, agent_blocks = 384;
    precompute_kernel<<<dim3(nbr_blocks + agent_blocks), dim3(256), 0, stream>>>(
        x_nbr, x_agent, W1, b1, Wa, ba, np, ap, (float*)d_out,
        n_nodes, n_agents, nbr_blocks);
    // grid 768 = 3 blocks/CU (best measured: R3 showed 8/CU is NOT better)
    edge_kernel<<<dim3(768), dim3(256), 0, stream>>>(
        np, ap, W2, b2, edge_src, (float*)d_out, n_tiles);
}

// Round 7
// 168.357 us; speedup vs baseline: 1.1875x; 1.1875x over previous
//
#include <hip/hip_runtime.h>

typedef unsigned int u32;
typedef unsigned short u16;
typedef __attribute__((ext_vector_type(2))) float f32x2;
typedef __attribute__((ext_vector_type(4))) float f32x4;
typedef __attribute__((ext_vector_type(8))) __bf16 bf16x8;
typedef __attribute__((ext_vector_type(4))) u32 u32x4;

// fp32 -> bf16 round-to-nearest-even
__device__ __forceinline__ u32 f2bf(float f) {
    u32 u = __builtin_bit_cast(u32, f);
    return (u + 0x7fffu + ((u >> 16) & 1u)) >> 16;
}
__device__ __forceinline__ u32 pk2(float lo, float hi) {
    return f2bf(lo) | (f2bf(hi) << 16);
}
// unpack bf16 pair from u32 (do NOT use __bf16 vector arithmetic on gfx950 —
// prior session showed it miscompiles; unpack to f32 explicitly)
__device__ __forceinline__ float bflo(u32 a) { return __builtin_bit_cast(float, a << 16); }
__device__ __forceinline__ float bfhi(u32 a) { return __builtin_bit_cast(float, a & 0xffff0000u); }

union LdsTile {
    u16 h[16 * 136];
    u32x4 v[16 * 17];
};

// ---------------------------------------------------------------------------
// Precompute kernel R13 (hybrid): R0's verified register-resident main loop
// + cheap weight prologue.
//   R6 lesson: weights in LDS put 8 ds_read_b128 + lgkm waits on every kk of
//   every tile (62us, VALUBusy 8.6%, 690K bank conflicts) — regression. But
//   R6 verified the staging mapping. R0's defect was only the prologue: 512
//   scattered scalar W1 loads/thread. Hybrid: coalesced W1->LDS staging (64
//   coalesced loads/thread), sync, ONE-TIME 32x ds_read_b128 to fill
//   wf[8][4] registers, then the untouched R0 main loop ((256,2), wf live in
//   VGPRs, ~220 regs, 8 waves/CU).
//   Fragment map (R6-verified): wfrag[nt][kk][q][n][jp] = pk2(W[k][col],
//   W[k+1][col]), k=kk*32+q*8+jp*2, col=nt*16+n; staged from row-pair
//   rp=k/2: kk=rp>>4, q=(rp>>2)&3, jp=rp&3.
// ---------------------------------------------------------------------------
__global__ __launch_bounds__(256, 2)
void precompute_kernel(const float* __restrict__ x_nbr,
                       const float* __restrict__ x_agent,
                       const float* __restrict__ W1,
                       const float* __restrict__ b1,
                       const float* __restrict__ Wa,
                       const float* __restrict__ ba,
                       u16* __restrict__ np, u16* __restrict__ ap,
                       float* __restrict__ out,
                       int n_nodes, int n_agents, int nbr_blocks)
{
    __shared__ LdsTile Abuf[4];
    __shared__ u32x4 wfrag[8][4][4][16];   // 32 KB: [nt][kk][q][n], elems [jp]
    const int wid = threadIdx.x >> 6;
    const int l   = threadIdx.x & 63;
    const int n   = l & 15;
    const int q   = l >> 4;
    const bool is_nbr = (int)blockIdx.x < nbr_blocks;

    const float* Wb = W1 + (is_nbr ? 0 : 128 * 128);

    // ---- cooperative W1-fragment staging (fully coalesced, once/block) ----
    {
        const int tid  = threadIdx.x;
        const int c    = tid & 127;         // column
        const int half = tid >> 7;          // 0/1: which row-pair this iter
#pragma unroll 4
        for (int it = 0; it < 32; ++it) {
            const int rp = it * 2 + half;   // row pair 0..63, k = 2*rp
            const int k  = rp * 2;
            const float f0 = Wb[(size_t)k * 128 + c];
            const float f1 = Wb[(size_t)(k + 1) * 128 + c];
            wfrag[c >> 4][rp >> 4][(rp >> 2) & 3][c & 15][rp & 3] = pk2(f0, f1);
        }
    }
    __syncthreads();

    // ---- one-time LDS -> register fill (32 ds_read_b128, pipelined) ----
    u32x4 wf[8][4];
#pragma unroll
    for (int nt = 0; nt < 8; ++nt)
#pragma unroll
        for (int kk = 0; kk < 4; ++kk)
            wf[nt][kk] = wfrag[nt][kk][q][n];

    const f32x4 zero = {0.f, 0.f, 0.f, 0.f};

    if (is_nbr) {
        const int n_tiles = n_nodes >> 4;
        const int gw = blockIdx.x * 4 + wid;
        const int stride = nbr_blocks * 4;
        for (int t = gw; t < n_tiles; t += stride) {
            const int a0 = t * 16;
#pragma unroll
            for (int it = 0; it < 4; ++it) {
                const int m = it * 4 + q;
                const float* bp = x_nbr + (size_t)(a0 + m) * 128 + n * 8;
                const float4 v0 = *(const float4*)bp;
                const float4 v1 = *(const float4*)(bp + 4);
                u32x4 pkv;
                pkv[0] = pk2(v0.x, v0.y); pkv[1] = pk2(v0.z, v0.w);
                pkv[2] = pk2(v1.x, v1.y); pkv[3] = pk2(v1.z, v1.w);
                Abuf[wid].v[m * 17 + n] = pkv;
            }
            f32x4 acc[8];
#pragma unroll
            for (int nt = 0; nt < 8; ++nt) acc[nt] = zero;
#pragma unroll
            for (int kk = 0; kk < 4; ++kk) {
                const u32x4 a = Abuf[wid].v[n * 17 + kk * 4 + q];
#pragma unroll
                for (int nt = 0; nt < 8; ++nt)
                    acc[nt] = __builtin_amdgcn_mfma_f32_16x16x32_bf16(
                        __builtin_bit_cast(bf16x8, a),
                        __builtin_bit_cast(bf16x8, wf[nt][kk]), acc[nt], 0, 0, 0);
            }
#pragma unroll
            for (int nt = 0; nt < 8; ++nt)
#pragma unroll
                for (int r = 0; r < 4; ++r)
                    np[(size_t)(a0 + q * 4 + r) * 128 + nt * 16 + n] =
                        (u16)f2bf(acc[nt][r]);
        }
    } else {
        u32x4 waf[4];
#pragma unroll
        for (int kk = 0; kk < 4; ++kk) {
            u32x4 w;
#pragma unroll
            for (int jp = 0; jp < 4; ++jp) {
                const int k = kk * 32 + q * 8 + jp * 2;
                const float f0 = (n < 8) ? Wa[(size_t)k * 8 + n] : 0.f;
                const float f1 = (n < 8) ? Wa[(size_t)(k + 1) * 8 + n] : 0.f;
                w[jp] = pk2(f0, f1);
            }
            waf[kk] = w;
        }
        float b1v[8];
#pragma unroll
        for (int nt = 0; nt < 8; ++nt) b1v[nt] = b1[nt * 16 + n];
        const float bav = (n < 8) ? ba[n] : 0.f;

        const int n_tiles = n_agents >> 4;
        const int agent_blocks = gridDim.x - nbr_blocks;
        const int gw = (blockIdx.x - nbr_blocks) * 4 + wid;
        const int stride = agent_blocks * 4;
        for (int t = gw; t < n_tiles; t += stride) {
            const int a0 = t * 16;
#pragma unroll
            for (int it = 0; it < 4; ++it) {
                const int m = it * 4 + q;
                const float* bp = x_agent + (size_t)(a0 + m) * 128 + n * 8;
                const float4 v0 = *(const float4*)bp;
                const float4 v1 = *(const float4*)(bp + 4);
                u32x4 pkv;
                pkv[0] = pk2(v0.x, v0.y); pkv[1] = pk2(v0.z, v0.w);
                pkv[2] = pk2(v1.x, v1.y); pkv[3] = pk2(v1.z, v1.w);
                Abuf[wid].v[m * 17 + n] = pkv;
            }
            f32x4 acc[8];
#pragma unroll
            for (int nt = 0; nt < 8; ++nt) acc[nt] = zero;
            f32x4 acca = zero;
#pragma unroll
            for (int kk = 0; kk < 4; ++kk) {
                const u32x4 a = Abuf[wid].v[n * 17 + kk * 4 + q];
#pragma unroll
                for (int nt = 0; nt < 8; ++nt)
                    acc[nt] = __builtin_amdgcn_mfma_f32_16x16x32_bf16(
                        __builtin_bit_cast(bf16x8, a),
                        __builtin_bit_cast(bf16x8, wf[nt][kk]), acc[nt], 0, 0, 0);
                acca = __builtin_amdgcn_mfma_f32_16x16x32_bf16(
                    __builtin_bit_cast(bf16x8, a),
                    __builtin_bit_cast(bf16x8, waf[kk]), acca, 0, 0, 0);
            }
#pragma unroll
            for (int nt = 0; nt < 8; ++nt)
#pragma unroll
                for (int r = 0; r < 4; ++r)
                    ap[(size_t)(a0 + q * 4 + r) * 128 + nt * 16 + n] =
                        (u16)f2bf(acc[nt][r] + b1v[nt]);
            const float4 z = {0.f, 0.f, 0.f, 0.f};
#pragma unroll
            for (int it = 0; it < 4; ++it) {
                const int m = it * 4 + q;
                float4* zp = (float4*)(out + (size_t)(a0 + m) * 264 + 128 + n * 8);
                zp[0] = z; zp[1] = z;
            }
#pragma unroll
            for (int r = 0; r < 4; ++r) {
                const int m = q * 4 + r;
                if (n < 8) out[(size_t)(a0 + m) * 264 + 256 + n] = acca[r] + bav;
            }
        }
    }
}

// ---------------------------------------------------------------------------
// Edge kernel R11 (UNCHANGED — verified 42.4us, VGPR 64, no spill):
// 2-deep ISA pipeline, progressive per-pair vmcnt waits, packed relu+cvt.
//   Ledger: per-step ops A=1 idx, B=8 gathers (interleaved np/ap), D=4
//   stores = 13. W1 wait vmcnt(13); compute pair kk waits 19-2kk.
//   Prologue pair kk waits 15-2kk. dst(tile t)==t (fixture structure).
// ---------------------------------------------------------------------------
struct GSet { u32x4 np[4]; u32x4 ap[4]; };

__device__ __forceinline__ void async_idx(const int* p, int& v) {
    asm volatile("global_load_dword %0, %1, off" : "=v"(v) : "v"(p) : "memory");
}
// 8 gathers, interleaved np/ap pairs so pair kk sits at FIFO slots 2kk+1,2kk+2
__device__ __forceinline__ void issue_block(const u16* npb, const u16* apb, GSet& g) {
    asm volatile(
        "global_load_dwordx4 %0, %8, off sc0\n\t"
        "global_load_dwordx4 %1, %9, off sc0\n\t"
        "global_load_dwordx4 %2, %8, off offset:64 sc0\n\t"
        "global_load_dwordx4 %3, %9, off offset:64 sc0\n\t"
        "global_load_dwordx4 %4, %8, off offset:128 sc0\n\t"
        "global_load_dwordx4 %5, %9, off offset:128 sc0\n\t"
        "global_load_dwordx4 %6, %8, off offset:192 sc0\n\t"
        "global_load_dwordx4 %7, %9, off offset:192 sc0"
        : "=&v"(g.np[0]), "=&v"(g.ap[0]), "=&v"(g.np[1]), "=&v"(g.ap[1]),
          "=&v"(g.np[2]), "=&v"(g.ap[2]), "=&v"(g.np[3]), "=&v"(g.ap[3])
        : "v"(npb), "v"(apb) : "memory");
}
__device__ __forceinline__ void issue_gathers(const u16* __restrict__ np,
                                              const u16* __restrict__ ap,
                                              int src_self, int t, int q, GSet& g)
{
    issue_block(np + (size_t)(unsigned)src_self * 128 + q * 8,
                ap + (size_t)(unsigned)t        * 128 + q * 8, g);
}

// two-level so the count macro-expands before stringification
#define WAITP_(N, a, b) \
    asm volatile("s_waitcnt vmcnt(" #N ")" : "+v"(a), "+v"(b) :: "memory")
#define WAITP(N, a, b) WAITP_(N, a, b)

// relu(a+b) on a packed bf16 pair -> packed bf16 (v_pk_add_f32 + cvt_pk RNE)
__device__ __forceinline__ u32 relu_pk(u32 av, u32 bv) {
    f32x2 a = {bflo(av), bfhi(av)};
    f32x2 b = {bflo(bv), bfhi(bv)};
    const f32x2 s = a + b;
    const float lo = fmaxf(s[0], 0.f);
    const float hi = fmaxf(s[1], 0.f);
    u32 r;
    asm("v_cvt_pk_bf16_f32 %0, %1, %2" : "=v"(r) : "v"(lo), "v"(hi));
    return r;
}
__device__ __forceinline__ u32x4 relu_pk4(const u32x4& a, const u32x4& b) {
    u32x4 hf;
    hf[0] = relu_pk(a[0], b[0]); hf[1] = relu_pk(a[1], b[1]);
    hf[2] = relu_pk(a[2], b[2]); hf[3] = relu_pk(a[3], b[3]);
    return hf;
}

#define MFMA_BF16(A, B, C) __builtin_amdgcn_mfma_f32_16x16x32_bf16( \
    __builtin_bit_cast(bf16x8, A), __builtin_bit_cast(bf16x8, B), (C), 0, 0, 0)

// compute one tile from G with progressive per-pair waits W0..W3, then store
#define COMPUTE_TILE(G, DST, W0, W1N, W2N, W3N) do {                          \
    f32x4 acc2 = {0.f, 0.f, 0.f, 0.f};                                        \
    WAITP(W0,  (G).np[0], (G).ap[0]);                                         \
    acc2 = MFMA_BF16(relu_pk4((G).np[0], (G).ap[0]), w2f[0], acc2);           \
    WAITP(W1N, (G).np[1], (G).ap[1]);                                         \
    acc2 = MFMA_BF16(relu_pk4((G).np[1], (G).ap[1]), w2f[1], acc2);           \
    WAITP(W2N, (G).np[2], (G).ap[2]);                                         \
    acc2 = MFMA_BF16(relu_pk4((G).np[2], (G).ap[2]), w2f[2], acc2);           \
    WAITP(W3N, (G).np[3], (G).ap[3]);                                         \
    acc2 = MFMA_BF16(relu_pk4((G).np[3], (G).ap[3]), w2f[3], acc2);           \
    float* orow = out + (size_t)(DST) * 264;                                  \
    _Pragma("unroll")                                                         \
    for (int r = 0; r < 4; ++r)                                               \
        if (n < 8) orow[(q * 4 + r) * 8 + n] = acc2[r] + b2v;                 \
} while (0)

// PC = parity of the tile being computed; PF = 1-PC (tile being fetched)
template<int PC>
__device__ __forceinline__ void pipe_step(const u16* __restrict__ np,
                                          const u16* __restrict__ ap,
                                          const int* __restrict__ edge_src,
                                          float* __restrict__ out,
                                          int t_c, int t_f, int t_a,
                                          int q, int n,
                                          int (&sreg)[2], GSet (&g)[2],
                                          const u32x4 (&w2f)[4], float b2v)
{
    constexpr int PF = 1 - PC;
    // A: src idx for tile t_a (overwrites sreg[PC]: its gathers issued last step)
    async_idx(edge_src + (size_t)t_a * 16 + n, sreg[PC]);
    // W1: src idx of tile t_f resident (13 newer: B(prev)8 + D(prev)4 + A 1)
    asm volatile("s_waitcnt vmcnt(13)" : "+v"(sreg[PF]) :: "memory");
    // B: gathers for tile t_f (dst == t_f, no load needed)
    issue_gathers(np, ap, sreg[PF], t_f, q, g[PF]);
    // compute tile t_c from g[PC] with progressive waits 19/17/15/13
    COMPUTE_TILE(g[PC], t_c, 19, 17, 15, 13);
}

__global__ __launch_bounds__(256, 3)
void edge_kernel(const u16* __restrict__ np, const u16* __restrict__ ap,
                 const float* __restrict__ W2, const float* __restrict__ b2,
                 const int* __restrict__ edge_src,
                 float* __restrict__ out, int n_tiles)
{
    const int wid = threadIdx.x >> 6;
    const int l   = threadIdx.x & 63;
    const int n   = l & 15;
    const int q   = l >> 4;

    u32x4 w2f[4];
#pragma unroll
    for (int kk = 0; kk < 4; ++kk) {
        u32x4 w;
#pragma unroll
        for (int jp = 0; jp < 4; ++jp) {
            const int k = kk * 32 + q * 8 + jp * 2;
            const float f0 = (n < 8) ? W2[(size_t)k * 8 + n] : 0.f;
            const float f1 = (n < 8) ? W2[(size_t)(k + 1) * 8 + n] : 0.f;
            w[jp] = pk2(f0, f1);
        }
        w2f[kk] = w;
    }
    const float b2v = (n < 8) ? b2[n] : 0.f;

    const int stride = gridDim.x * 4;
    const int gw = blockIdx.x * 4 + wid;
    if (gw >= n_tiles) return;
    const int nt_w = (n_tiles - gw + stride - 1) / stride;

    int t_c = gw;
    int t_f = (t_c + stride < n_tiles) ? t_c + stride : t_c;
    int t_a = (t_f + stride < n_tiles) ? t_f + stride : t_f;

    int sreg[2];
    GSet g[2];

    // ---- prologue: A0, A1, wait(0), B0, A2, B1, compute0(prog waits) ----
    async_idx(edge_src + (size_t)t_c * 16 + n, sreg[0]);
    async_idx(edge_src + (size_t)t_f * 16 + n, sreg[1]);
    asm volatile("s_waitcnt vmcnt(0)" : "+v"(sreg[0]), "+v"(sreg[1]) :: "memory");
    issue_gathers(np, ap, sreg[0], t_c, q, g[0]);           // B0 (8)
    async_idx(edge_src + (size_t)t_a * 16 + n, sreg[0]);    // A2 (1) — sreg[0] free
    issue_gathers(np, ap, sreg[1], t_f, q, g[1]);           // B1 (8)
    // pair kk of B0: newer = rest-of-B0 (6-2kk) + A2 1 + B1 8 = 15-2kk
    COMPUTE_TILE(g[0], t_c, 15, 13, 11, 9);                 // D0 (4)

    // ---- steady loop: tile i uses g[i&1]; src regs by same parity ----
    int i = 1;
    while (true) {
        if (i >= nt_w) break;
        t_c = t_f; t_f = t_a;
        t_a = (t_a + stride < n_tiles) ? t_a + stride : t_a;
        pipe_step<1>(np, ap, edge_src, out, t_c, t_f, t_a,
                     q, n, sreg, g, w2f, b2v);
        if (++i >= nt_w) break;
        t_c = t_f; t_f = t_a;
        t_a = (t_a + stride < n_tiles) ? t_a + stride : t_a;
        pipe_step<0>(np, ap, edge_src, out, t_c, t_f, t_a,
                     q, n, sreg, g, w2f, b2v);
        ++i;
    }
}

extern "C" void kernel_launch(void* const* d_in, const int* in_sizes, int n_in,
                              void* d_out, int out_size, void* d_ws, size_t ws_size,
                              hipStream_t stream)
{
    const float* x_nbr   = (const float*)d_in[0];
    const float* x_agent = (const float*)d_in[1];
    const float* W1      = (const float*)d_in[2];
    const float* b1      = (const float*)d_in[3];
    const float* W2      = (const float*)d_in[4];
    const float* b2      = (const float*)d_in[5];
    const float* Wa      = (const float*)d_in[6];
    const float* ba      = (const float*)d_in[7];
    const int* edge_src  = (const int*)d_in[8];

    const int E        = in_sizes[8];
    const int n_nodes  = in_sizes[0] / 128;
    const int n_agents = in_sizes[1] / 128;
    const int n_tiles  = E / 16;

    u16* np = (u16*)d_ws;
    u16* ap = (u16*)d_ws + (size_t)n_nodes * 128;

    // back to the R0/R5 verified grid: 512+512, (256,2), 8 waves/CU
    const int nbr_blocks = 512, agent_blocks = 512;
    precompute_kernel<<<dim3(nbr_blocks + agent_blocks), dim3(256), 0, stream>>>(
        x_nbr, x_agent, W1, b1, Wa, ba, np, ap, (float*)d_out,
        n_nodes, n_agents, nbr_blocks);
    // grid 768 = 3 blocks/CU (best measured: R3 showed 8/CU is NOT better)
    edge_kernel<<<dim3(768), dim3(256), 0, stream>>>(
        np, ap, W2, b2, edge_src, (float*)d_out, n_tiles);
}